// Round 1
// baseline (30.624 us; speedup 1.0000x reference)
//
#include <hip/hip_runtime.h>

#define NQ   12
#define DIM  4096   // 2^12

__device__ __forceinline__ float2 mkc(float a, float b) { float2 r; r.x = a; r.y = b; return r; }
__device__ __forceinline__ float2 cmul(float2 a, float2 b) {
    return mkc(a.x * b.x - a.y * b.y, a.x * b.y + a.y * b.x);
}
__device__ __forceinline__ float2 cadd(float2 a, float2 b) { return mkc(a.x + b.x, a.y + b.y); }

struct cmat { float2 m[4]; };  // row-major [[m0 m1],[m2 m3]]

__device__ __forceinline__ cmat mmul(const cmat& A, const cmat& B) {
    cmat R;
    R.m[0] = cadd(cmul(A.m[0], B.m[0]), cmul(A.m[1], B.m[2]));
    R.m[1] = cadd(cmul(A.m[0], B.m[1]), cmul(A.m[1], B.m[3]));
    R.m[2] = cadd(cmul(A.m[2], B.m[0]), cmul(A.m[3], B.m[2]));
    R.m[3] = cadd(cmul(A.m[2], B.m[1]), cmul(A.m[3], B.m[3]));
    return R;
}
__device__ __forceinline__ cmat rxm(float t) {
    float c = cosf(0.5f * t), s = sinf(0.5f * t);
    cmat R; R.m[0] = mkc(c, 0.f); R.m[1] = mkc(0.f, -s); R.m[2] = mkc(0.f, -s); R.m[3] = mkc(c, 0.f);
    return R;
}
__device__ __forceinline__ cmat rym(float t) {
    float c = cosf(0.5f * t), s = sinf(0.5f * t);
    cmat R; R.m[0] = mkc(c, 0.f); R.m[1] = mkc(-s, 0.f); R.m[2] = mkc(s, 0.f); R.m[3] = mkc(c, 0.f);
    return R;
}

// iSWAP on bit positions (p, p+1): amps with bits (p,p+1) = (1,0)/(0,1) swap ×i.
__device__ __forceinline__ void iswap_pass(float2* st, int p, int t) {
    #pragma unroll
    for (int r = 0; r < 4; ++r) {
        int m    = t + (r << 8);                 // [0, 1024)
        int low  = m & ((1 << p) - 1);
        int high = (m >> p) << (p + 2);
        int f00  = high | low;
        int fA   = f00 | (1 << p);
        int fB   = f00 | (2 << p);
        float2 a = st[fA], b = st[fB];
        st[fA] = mkc(-b.y, b.x);                 // i * b
        st[fB] = mkc(-a.y, a.x);                 // i * a
    }
}

// single-qubit gate (2x2 u[4]) on bit position p
__device__ __forceinline__ void sq_pass(float2* st, const float2* u, int p, int t) {
    float2 u0 = u[0], u1 = u[1], u2 = u[2], u3 = u[3];
    #pragma unroll
    for (int r = 0; r < 8; ++r) {
        int m  = t + (r << 8);                   // [0, 2048)
        int f0 = ((m >> p) << (p + 1)) | (m & ((1 << p) - 1));
        int f1 = f0 | (1 << p);
        float2 s0 = st[f0], s1 = st[f1];
        st[f0] = cadd(cmul(u0, s0), cmul(u1, s1));
        st[f1] = cadd(cmul(u2, s0), cmul(u3, s1));
    }
}

__global__ __launch_bounds__(256) void qcnn_kernel(
    const float* __restrict__ x,        // (B,1,14,14)
    const float* __restrict__ conv_w,   // (1,1,4,4)
    const float* __restrict__ conv_b,   // (1,)
    const float* __restrict__ qw,       // (3,)
    float* __restrict__ out)            // (B,2)
{
    __shared__ float2 st[DIM];          // 32 KB statevector
    __shared__ float  ang[36];
    __shared__ float2 c0s[12][2];       // layer-1 combined U, column 0 (product-state init)
    __shared__ float2 u2s[12][4];       // layer-2 combined U, full 2x2
    __shared__ float2 Wm[4];            // final gate on wire 0
    __shared__ float  redp[8];

    const int b = blockIdx.x;
    const int t = threadIdx.x;

    // ---- conv (valid, stride 2, 4x4 kernel): 36 angles ----
    if (t < 36) {
        int oy = t / 6, ox = t % 6;
        const float* xb = x + b * 196;
        float acc = conv_b[0];
        #pragma unroll
        for (int ky = 0; ky < 4; ++ky)
            #pragma unroll
            for (int kx = 0; kx < 4; ++kx)
                acc += xb[(oy * 2 + ky) * 14 + (ox * 2 + kx)] * conv_w[ky * 4 + kx];
        ang[t] = acc;
    }
    __syncthreads();

    // ---- precombine per-qubit gate matrices ----
    if (t < 12) {
        int i   = t >> 1;
        int off = (t & 1) * 3;
        float a0 = ang[i * 6 + off], a1 = ang[i * 6 + off + 1], a2 = ang[i * 6 + off + 2];
        // layer 1: applied Rx(a0), Ry(a1), Rx(a2)  =>  U1 = Rx(a2) @ Ry(a1) @ Rx(a0)
        cmat U1 = mmul(rxm(a2), mmul(rym(a1), rxm(a0)));
        c0s[t][0] = U1.m[0];   // U1[0][0]
        c0s[t][1] = U1.m[2];   // U1[1][0]
        // layer 2: applied Ry(a0), Rx(a1), Ry(a2)  =>  U2 = Ry(a2) @ Rx(a1) @ Ry(a0)
        cmat U2 = mmul(rym(a2), mmul(rxm(a1), rym(a0)));
        u2s[t][0] = U2.m[0]; u2s[t][1] = U2.m[1]; u2s[t][2] = U2.m[2]; u2s[t][3] = U2.m[3];
    } else if (t == 12) {
        // final: applied Rx(qw0), Ry(qw1), Rx(qw2) => W = Rx(qw2) @ Ry(qw1) @ Rx(qw0)
        cmat W = mmul(rxm(qw[2]), mmul(rym(qw[1]), rxm(qw[0])));
        Wm[0] = W.m[0]; Wm[1] = W.m[1]; Wm[2] = W.m[2]; Wm[3] = W.m[3];
    }
    __syncthreads();

    // ---- init: |0..0> through layer-1 product of single-qubit gates => product state ----
    // flat index f: wire w <-> bit (11-w). f = t | (k<<8): bits 0..7 from t (wires 11..4),
    // bits 8..11 from k (wires 3..0).
    {
        float2 base = mkc(1.f, 0.f);
        #pragma unroll
        for (int p = 0; p < 8; ++p)
            base = cmul(base, c0s[11 - p][(t >> p) & 1]);
        #pragma unroll
        for (int k = 0; k < 16; ++k) {
            float2 amp = base;
            #pragma unroll
            for (int p = 8; p < 12; ++p)
                amp = cmul(amp, c0s[11 - p][(k >> (p - 8)) & 1]);
            st[(k << 8) | t] = amp;
        }
    }
    __syncthreads();

    // ---- first iSWAP chain: wires (11,10),(10,9),...,(1,0) = bits (0,1),(1,2),...,(10,11) ----
    for (int p = 0; p <= 10; ++p) {
        iswap_pass(st, p, t);
        __syncthreads();
    }

    // ---- layer-2 single-qubit gates (order across qubits irrelevant; passes serialized) ----
    for (int w = 0; w < 12; ++w) {
        sq_pass(st, u2s[w], 11 - w, t);
        __syncthreads();
    }

    // ---- second iSWAP chain: wires (1,0),(2,1),...,(11,10) = bits (10,11),(9,10),...,(0,1) ----
    for (int p = 10; p >= 0; --p) {
        iswap_pass(st, p, t);
        __syncthreads();
    }

    // ---- final gate on wire 0 (bit 11), fused with |amp|^2 marginal reduction ----
    float p0 = 0.f, p1 = 0.f;
    {
        float2 u0 = Wm[0], u1 = Wm[1], u2 = Wm[2], u3 = Wm[3];
        #pragma unroll
        for (int r = 0; r < 8; ++r) {
            int f0 = t + (r << 8);      // [0, 2048): bit11 = 0
            int f1 = f0 | 2048;
            float2 s0 = st[f0], s1 = st[f1];
            float2 n0 = cadd(cmul(u0, s0), cmul(u1, s1));
            float2 n1 = cadd(cmul(u2, s0), cmul(u3, s1));
            p0 += n0.x * n0.x + n0.y * n0.y;
            p1 += n1.x * n1.x + n1.y * n1.y;
        }
    }
    // wave (64-lane) reduction, then cross-wave via LDS
    #pragma unroll
    for (int off = 32; off >= 1; off >>= 1) {
        p0 += __shfl_down(p0, off);
        p1 += __shfl_down(p1, off);
    }
    int wid = t >> 6;
    if ((t & 63) == 0) { redp[wid] = p0; redp[4 + wid] = p1; }
    __syncthreads();
    if (t == 0) {
        float a = redp[0] + redp[1] + redp[2] + redp[3];
        float c = redp[4] + redp[5] + redp[6] + redp[7];
        out[b * 2 + 0] = a;
        out[b * 2 + 1] = c;
    }
}

extern "C" void kernel_launch(void* const* d_in, const int* in_sizes, int n_in,
                              void* d_out, int out_size, void* d_ws, size_t ws_size,
                              hipStream_t stream) {
    const float* x      = (const float*)d_in[0];
    const float* conv_w = (const float*)d_in[1];
    const float* conv_b = (const float*)d_in[2];
    const float* qw     = (const float*)d_in[3];
    float* out          = (float*)d_out;

    int B = in_sizes[0] / 196;   // (B,1,14,14)
    qcnn_kernel<<<dim3(B), dim3(256), 0, stream>>>(x, conv_w, conv_b, qw, out);
}

// Round 2
// 11.035 us; speedup vs baseline: 2.7752x; 2.7752x over previous
//
#include <hip/hip_runtime.h>

__device__ __forceinline__ float2 mkc(float a, float b) { float2 r; r.x = a; r.y = b; return r; }
__device__ __forceinline__ float2 cmul(float2 a, float2 b) {
    return mkc(a.x * b.x - a.y * b.y, a.x * b.y + a.y * b.x);
}
__device__ __forceinline__ float2 cadd(float2 a, float2 b) { return mkc(a.x + b.x, a.y + b.y); }

// multiply by i^m (m in 0..3)
__device__ __forceinline__ float2 irot(float2 v, int m) {
    switch (m & 3) {
        case 0:  return v;
        case 1:  return mkc(-v.y, v.x);
        case 2:  return mkc(-v.x, -v.y);
        default: return mkc(v.y, -v.x);
    }
}

struct cmat { float2 m[4]; };  // row-major [[m0 m1],[m2 m3]]

__device__ __forceinline__ cmat mmul(const cmat& A, const cmat& B) {
    cmat R;
    R.m[0] = cadd(cmul(A.m[0], B.m[0]), cmul(A.m[1], B.m[2]));
    R.m[1] = cadd(cmul(A.m[0], B.m[1]), cmul(A.m[1], B.m[3]));
    R.m[2] = cadd(cmul(A.m[2], B.m[0]), cmul(A.m[3], B.m[2]));
    R.m[3] = cadd(cmul(A.m[2], B.m[1]), cmul(A.m[3], B.m[3]));
    return R;
}
__device__ __forceinline__ cmat rxm(float t) {
    float c = cosf(0.5f * t), s = sinf(0.5f * t);
    cmat R; R.m[0] = mkc(c, 0.f); R.m[1] = mkc(0.f, -s); R.m[2] = mkc(0.f, -s); R.m[3] = mkc(c, 0.f);
    return R;
}
__device__ __forceinline__ cmat rym(float t) {
    float c = cosf(0.5f * t), s = sinf(0.5f * t);
    cmat R; R.m[0] = mkc(c, 0.f); R.m[1] = mkc(-s, 0.f); R.m[2] = mkc(s, 0.f); R.m[3] = mkc(c, 0.f);
    return R;
}

// single-qubit gate on local k-bit J over a[16]
template<int J>
__device__ __forceinline__ void gate16(float2 (&a)[16], float2 g0, float2 g1, float2 g2, float2 g3) {
    #pragma unroll
    for (int m = 0; m < 16; ++m) {
        if (!(m & (1 << J))) {
            float2 s0 = a[m], s1 = a[m | (1 << J)];
            a[m]            = cadd(cmul(g0, s0), cmul(g1, s1));
            a[m | (1 << J)] = cadd(cmul(g2, s0), cmul(g3, s1));
        }
    }
}

__global__ __launch_bounds__(256) void qcnn_kernel(
    const float* __restrict__ x,        // (B,1,14,14)
    const float* __restrict__ conv_w,   // (1,1,4,4)
    const float* __restrict__ conv_b,   // (1,)
    const float* __restrict__ qw,       // (3,)
    float* __restrict__ out)            // (B,2)
{
    __shared__ float  ang[36];
    __shared__ float2 c0s[12][2];   // layer-1 combined U per wire, column 0
    __shared__ float2 g10m[4];      // layer-2 combined U, wire 1 (bit 10)
    __shared__ float2 g11m[4];      // layer-2 combined U, wire 0 (bit 11)
    __shared__ float2 Wm[4];        // final gate, wire 0 (bit 11)
    __shared__ float2 KT[16];       // per-k init factor with i^(phase(k)) folded in
    __shared__ float  redp[8];

    const int b = blockIdx.x;
    const int t = threadIdx.x;

    // ---- conv (valid, stride 2, 4x4): 36 angles ----
    if (t < 36) {
        int oy = t / 6, ox = t % 6;
        const float* xb = x + b * 196;
        float acc = conv_b[0];
        #pragma unroll
        for (int ky = 0; ky < 4; ++ky)
            #pragma unroll
            for (int kx = 0; kx < 4; ++kx)
                acc += xb[(oy * 2 + ky) * 14 + (ox * 2 + kx)] * conv_w[ky * 4 + kx];
        ang[t] = acc;
    }
    __syncthreads();

    // ---- per-wire combined gate matrices ----
    if (t < 12) {
        int i   = t >> 1;
        int off = (t & 1) * 3;
        float a0 = ang[i * 6 + off], a1 = ang[i * 6 + off + 1], a2 = ang[i * 6 + off + 2];
        // layer 1: Rx(a0),Ry(a1),Rx(a2) applied => U1 = Rx(a2) Ry(a1) Rx(a0); need column 0 only
        cmat U1 = mmul(rxm(a2), mmul(rym(a1), rxm(a0)));
        c0s[t][0] = U1.m[0];
        c0s[t][1] = U1.m[2];
        // layer 2: Ry(a0),Rx(a1),Ry(a2) => U2 = Ry(a2) Rx(a1) Ry(a0); only wires 0,1 survive
        if (t < 2) {
            cmat U2 = mmul(rym(a2), mmul(rxm(a1), rym(a0)));
            float2* dst = (t == 0) ? g11m : g10m;   // wire0 -> bit11, wire1 -> bit10
            dst[0] = U2.m[0]; dst[1] = U2.m[1]; dst[2] = U2.m[2]; dst[3] = U2.m[3];
        }
    } else if (t == 12) {
        cmat W = mmul(rxm(qw[2]), mmul(rym(qw[1]), rxm(qw[0])));
        Wm[0] = W.m[0]; Wm[1] = W.m[1]; Wm[2] = W.m[2]; Wm[3] = W.m[3];
    }
    __syncthreads();

    // ---- KT[k]: k = f bits 8..11. With h = rol12(f): h bit9 = f8 (wire 2), h bit10 = f9
    // (wire 1), h bit11 = f10 (wire 0), h bit0 = f11 (wire 11). Fold i^(k-part of phase).
    if (t < 16) {
        int k = t;
        float2 v = cmul(cmul(c0s[2][k & 1], c0s[1][(k >> 1) & 1]),
                        cmul(c0s[0][(k >> 2) & 1], c0s[11][(k >> 3) & 1]));
        int pck = __popc(k & 7);
        int e = ((k < 8) ? pck : (11 - pck)) & 3;
        KT[k] = irot(v, e);
    }
    __syncthreads();

    // ---- per-thread base product over f bits 0..7 (= h bits 1..8 = wires 10..3) ----
    float2 Bp = c0s[10][t & 1];
    #pragma unroll
    for (int j = 1; j < 8; ++j)
        Bp = cmul(Bp, c0s[10 - j][(t >> j) & 1]);
    int pcT = __popc(t) & 3;
    float2 P = irot(Bp, pcT);            // for k < 8 (f bit11 = 0): phase i^(pcT+pck)
    float2 Q = irot(Bp, (4 - pcT) & 3);  // for k >= 8: phase i^(11-pcT-pck)

    // ---- state after forward iSWAP chain, 16 amps (f = t | k<<8) in registers ----
    float2 a[16];
    #pragma unroll
    for (int k = 0; k < 16; ++k)
        a[k] = cmul((k < 8) ? P : Q, KT[k]);

    // ---- G10 (k bit 2), G11 (k bit 3) ----
    gate16<2>(a, g10m[0], g10m[1], g10m[2], g10m[3]);
    gate16<3>(a, g11m[0], g11m[1], g11m[2], g11m[3]);

    // ---- reverse-chain head: iSWAP on k bits (2,3) ----
    #pragma unroll
    for (int m = 0; m < 4; ++m) {
        float2 u = a[m | 4], v = a[m | 8];
        a[m | 4] = mkc(-v.y, v.x);
        a[m | 8] = mkc(-u.y, u.x);
    }

    // ---- W on k bit 3, fused with |amp|^2 marginal over bit 11 ----
    float p0 = 0.f, p1 = 0.f;
    {
        float2 w0 = Wm[0], w1 = Wm[1], w2 = Wm[2], w3 = Wm[3];
        #pragma unroll
        for (int k = 0; k < 8; ++k) {
            float2 s0 = a[k], s1 = a[k | 8];
            float2 n0 = cadd(cmul(w0, s0), cmul(w1, s1));
            float2 n1 = cadd(cmul(w2, s0), cmul(w3, s1));
            p0 += n0.x * n0.x + n0.y * n0.y;
            p1 += n1.x * n1.x + n1.y * n1.y;
        }
    }

    // ---- block reduction ----
    #pragma unroll
    for (int off = 32; off >= 1; off >>= 1) {
        p0 += __shfl_down(p0, off);
        p1 += __shfl_down(p1, off);
    }
    int wid = t >> 6;
    if ((t & 63) == 0) { redp[wid] = p0; redp[4 + wid] = p1; }
    __syncthreads();
    if (t == 0) {
        out[b * 2 + 0] = redp[0] + redp[1] + redp[2] + redp[3];
        out[b * 2 + 1] = redp[4] + redp[5] + redp[6] + redp[7];
    }
}

extern "C" void kernel_launch(void* const* d_in, const int* in_sizes, int n_in,
                              void* d_out, int out_size, void* d_ws, size_t ws_size,
                              hipStream_t stream) {
    const float* x      = (const float*)d_in[0];
    const float* conv_w = (const float*)d_in[1];
    const float* conv_b = (const float*)d_in[2];
    const float* qw     = (const float*)d_in[3];
    float* out          = (float*)d_out;

    int B = in_sizes[0] / 196;   // (B,1,14,14)
    qcnn_kernel<<<dim3(B), dim3(256), 0, stream>>>(x, conv_w, conv_b, qw, out);
}

// Round 3
// 9.655 us; speedup vs baseline: 3.1719x; 1.1430x over previous
//
#include <hip/hip_runtime.h>

__device__ __forceinline__ float2 mkc(float a, float b) { float2 r; r.x = a; r.y = b; return r; }
__device__ __forceinline__ float2 cmul(float2 a, float2 b) {
    return mkc(a.x * b.x - a.y * b.y, a.x * b.y + a.y * b.x);
}
__device__ __forceinline__ float2 cadd(float2 a, float2 b) { return mkc(a.x + b.x, a.y + b.y); }
__device__ __forceinline__ float2 muli(float2 a) { return mkc(-a.y, a.x); }       // * i
__device__ __forceinline__ float2 irot(float2 v, int m) {                          // * i^m
    m &= 3;
    if (m == 1) return mkc(-v.y, v.x);
    if (m == 2) return mkc(-v.x, -v.y);
    if (m == 3) return mkc(v.y, -v.x);
    return v;
}

struct cmat { float2 m[4]; };  // row-major [[m0 m1],[m2 m3]]

__device__ __forceinline__ cmat mmul(const cmat& A, const cmat& B) {
    cmat R;
    R.m[0] = cadd(cmul(A.m[0], B.m[0]), cmul(A.m[1], B.m[2]));
    R.m[1] = cadd(cmul(A.m[0], B.m[1]), cmul(A.m[1], B.m[3]));
    R.m[2] = cadd(cmul(A.m[2], B.m[0]), cmul(A.m[3], B.m[2]));
    R.m[3] = cadd(cmul(A.m[2], B.m[1]), cmul(A.m[3], B.m[3]));
    return R;
}
__device__ __forceinline__ cmat rxm(float t) {
    float c, s; __sincosf(0.5f * t, &s, &c);
    cmat R; R.m[0] = mkc(c, 0.f); R.m[1] = mkc(0.f, -s); R.m[2] = mkc(0.f, -s); R.m[3] = mkc(c, 0.f);
    return R;
}
__device__ __forceinline__ cmat rym(float t) {
    float c, s; __sincosf(0.5f * t, &s, &c);
    cmat R; R.m[0] = mkc(c, 0.f); R.m[1] = mkc(-s, 0.f); R.m[2] = mkc(s, 0.f); R.m[3] = mkc(c, 0.f);
    return R;
}

// column 0 of Rx(a2) @ Ry(a1) @ Rx(a0)   (layer-1 combined gate applied to |0>)
__device__ __forceinline__ void rxryrx_col0(float a0, float a1, float a2, float2& A, float2& B) {
    float s0, c0, s1, c1, s2, c2;
    __sincosf(0.5f * a0, &s0, &c0);
    __sincosf(0.5f * a1, &s1, &c1);
    __sincosf(0.5f * a2, &s2, &c2);
    // after Rx(a0): A=(c0,0), B=(0,-s0); after Ry(a1):
    float2 A1 = mkc(c1 * c0,  s1 * s0);
    float2 B1 = mkc(s1 * c0, -c1 * s0);
    // after Rx(a2): A = c2*A1 - i*s2*B1 ; B = -i*s2*A1 + c2*B1
    A = mkc(c2 * A1.x + s2 * B1.y, c2 * A1.y - s2 * B1.x);
    B = mkc(c2 * B1.x + s2 * A1.y, c2 * B1.y - s2 * A1.x);
}

__global__ __launch_bounds__(64) void qcnn_kernel(
    const float* __restrict__ x,        // (B,1,14,14)
    const float* __restrict__ conv_w,   // (1,1,4,4)
    const float* __restrict__ conv_b,   // (1,)
    const float* __restrict__ qw,       // (3,)
    float* __restrict__ out)            // (B,2)
{
    const int b = blockIdx.x;
    const int t = threadIdx.x;          // one wave: 0..63

    // ---- conv (valid, stride 2, 4x4): lane t<36 computes angle t ----
    float ang = 0.f;
    if (t < 36) {
        int oy = t / 6, ox = t - oy * 6;
        const float* xb = x + b * 196 + oy * 28 + ox * 2;
        float acc = conv_b[0];
        #pragma unroll
        for (int ky = 0; ky < 4; ++ky)
            #pragma unroll
            for (int kx = 0; kx < 4; ++kx)
                acc += xb[ky * 14 + kx] * conv_w[ky * 4 + kx];
        ang = acc;
    }

    // ---- broadcast the angles needed wave-wide ----
    float a00 = __shfl(ang, 0),  a01 = __shfl(ang, 1),  a02 = __shfl(ang, 2);   // wire 0
    float a10 = __shfl(ang, 3),  a11 = __shfl(ang, 4),  a12 = __shfl(ang, 5);   // wire 1
    float aB0 = __shfl(ang, 33), aB1 = __shfl(ang, 34), aB2 = __shfl(ang, 35);  // wire 11

    // per-lane angles for wire w = t (used for wires 1..10)
    int base = (t < 12) ? ((t >> 1) * 6 + (t & 1) * 3) : 0;
    float g0 = __shfl(ang, base), g1 = __shfl(ang, base + 1), g2 = __shfl(ang, base + 2);

    // ---- per-wire probability terms for wires 1..10 (bits 0..9 after permutation) ----
    float2 termC = mkc(1.f, 0.f);   // q0 + i*q1  (for G(i))
    float  termR = 1.f;             // q0 - q1    (for G(-1))
    if (t >= 1 && t <= 10) {
        float2 A, B; rxryrx_col0(g0, g1, g2, A, B);
        float q0 = A.x * A.x + A.y * A.y;
        float q1 = B.x * B.x + B.y * B.y;
        termC = mkc(q0, q1);
        termR = q0 - q1;
    }
    // xor-butterfly product over lanes 0..15 (lanes 0,11..15 hold identity)
    #pragma unroll
    for (int m = 1; m < 16; m <<= 1) {
        float2 o = mkc(__shfl_xor(termC.x, m, 16), __shfl_xor(termC.y, m, 16));
        float  orr = __shfl_xor(termR, m, 16);
        termC = cmul(termC, o);
        termR *= orr;
    }
    float Gi_re = termC.x, Gi_im = termC.y, Gm = termR;

    // ---- small shared matrices, computed redundantly in every lane ----
    float2 v10_0, v10_1; rxryrx_col0(a00, a01, a02, v10_0, v10_1);  // wire 0  -> bit 10
    float2 v11_0, v11_1; rxryrx_col0(aB0, aB1, aB2, v11_0, v11_1);  // wire 11 -> bit 11
    cmat G11 = mmul(rym(a02), mmul(rxm(a01), rym(a00)));            // wire 0 layer-2 -> bit 11
    cmat G10 = mmul(rym(a12), mmul(rxm(a11), rym(a10)));            // wire 1 layer-2 -> bit 10
    cmat W   = mmul(rxm(qw[2]), mmul(rym(qw[1]), rxm(qw[0])));      // final, bit 11

    // ---- r = popcount bucket handled by this lane (lanes 0..3 meaningful) ----
    int r = t & 3;
    float sgn = (r & 1) ? -1.f : 1.f;
    float re2 = (r == 0) ?  2.f * Gi_re :
                (r == 1) ?  2.f * Gi_im :
                (r == 2) ? -2.f * Gi_re : -2.f * Gi_im;
    float Sr = 0.25f * (1.f + sgn * Gm + re2);

    float2 cr  = mkc((r == 0) ? 1.f : (r == 2) ? -1.f : 0.f,
                     (r == 1) ? 1.f : (r == 3) ? -1.f : 0.f);   // i^r
    float2 crc = mkc(cr.x, -cr.y);                              // i^-r

    // phi_r on (β10, β11); s index = (β11<<1)|β10
    float2 p00 = cmul(v10_0, v11_0);
    float2 p10 = cmul(v10_1, v11_0);
    float2 p01 = cmul(v10_0, v11_1);
    float2 p11 = cmul(v10_1, v11_1);
    float2 s0 = cmul(cr,  p00);              // i^(r)      * p00
    float2 s1 = cmul(cr,  muli(p10));        // i^(r+1)    * p10
    float2 s2 = cmul(crc, irot(p01, 3));     // i^(11-r)   * p01
    float2 s3 = cmul(crc, irot(p11, 2));     // i^(10-r)   * p11

    // G10 on β10: pairs (s0,s1),(s2,s3)
    {
        float2 n0 = cadd(cmul(G10.m[0], s0), cmul(G10.m[1], s1));
        float2 n1 = cadd(cmul(G10.m[2], s0), cmul(G10.m[3], s1));
        float2 n2 = cadd(cmul(G10.m[0], s2), cmul(G10.m[1], s3));
        float2 n3 = cadd(cmul(G10.m[2], s2), cmul(G10.m[3], s3));
        s0 = n0; s1 = n1; s2 = n2; s3 = n3;
    }
    // G11 on β11: pairs (s0,s2),(s1,s3)
    {
        float2 n0 = cadd(cmul(G11.m[0], s0), cmul(G11.m[1], s2));
        float2 n2 = cadd(cmul(G11.m[2], s0), cmul(G11.m[3], s2));
        float2 n1 = cadd(cmul(G11.m[0], s1), cmul(G11.m[1], s3));
        float2 n3 = cadd(cmul(G11.m[2], s1), cmul(G11.m[3], s3));
        s0 = n0; s1 = n1; s2 = n2; s3 = n3;
    }
    // iSWAP on bits (10,11): s1 <-> s2, each * i
    {
        float2 u = s1, v = s2;
        s1 = muli(v);
        s2 = muli(u);
    }
    // W on β11 fused with marginal:  T_r(j)
    float T0, T1;
    {
        float2 n00 = cadd(cmul(W.m[0], s0), cmul(W.m[1], s2));
        float2 n01 = cadd(cmul(W.m[0], s1), cmul(W.m[1], s3));
        float2 n10 = cadd(cmul(W.m[2], s0), cmul(W.m[3], s2));
        float2 n11 = cadd(cmul(W.m[2], s1), cmul(W.m[3], s3));
        T0 = n00.x * n00.x + n00.y * n00.y + n01.x * n01.x + n01.y * n01.y;
        T1 = n10.x * n10.x + n10.y * n10.y + n11.x * n11.x + n11.y * n11.y;
    }

    float p0 = Sr * T0, p1 = Sr * T1;
    // sum the 4 r-buckets (lanes 0..3)
    p0 += __shfl_xor(p0, 1, 4);  p0 += __shfl_xor(p0, 2, 4);
    p1 += __shfl_xor(p1, 1, 4);  p1 += __shfl_xor(p1, 2, 4);

    if (t == 0) {
        out[b * 2 + 0] = p0;
        out[b * 2 + 1] = p1;
    }
}

extern "C" void kernel_launch(void* const* d_in, const int* in_sizes, int n_in,
                              void* d_out, int out_size, void* d_ws, size_t ws_size,
                              hipStream_t stream) {
    const float* x      = (const float*)d_in[0];
    const float* conv_w = (const float*)d_in[1];
    const float* conv_b = (const float*)d_in[2];
    const float* qw     = (const float*)d_in[3];
    float* out          = (float*)d_out;

    int B = in_sizes[0] / 196;   // (B,1,14,14)
    qcnn_kernel<<<dim3(B), dim3(64), 0, stream>>>(x, conv_w, conv_b, qw, out);
}